// Round 6
// baseline (660.615 us; speedup 1.0000x reference)
//
#include <hip/hip_runtime.h>
#include <hip/hip_bf16.h>
#include <math.h>

// SharedLora on MI355X — round 6: thread-per-bin, minimal live set.
// r5 lesson: traffic was fine (202 MB) but 128 VGPR -> 4 waves/SIMD -> latency
// exposed (345 us vs ~30 us issue time). r6 shrinks per-thread state:
//   phase A (tid<250): cs[20] = L5+L4+L3+L2+L1+L0 (for w only), x6[20],
//     c-loop: y6 = C^T x6, ys = C^T cs; w = bias+y6+ys; q += y6^2 (L6 quad).
//   phase B: per-tile exclusive L5/L4/L3 columns, y-quad from L1-hot re-read.
//   L0-2 quads in k_klc. comp via wave-uniform s_loads. w stored bf16.

#define NROI 256
#define NC 20
#define NFINAL 8000
#define NCUTS 500000
#define TBINS 250
#define NTILE 32           // 8000 / TBINS

// q += sum_c (sum_a comp[a][c] * x[a])^2   (comp via uniform scalar loads)
#define YQUAD(x)                                            \
    do {                                                    \
        _Pragma("unroll")                                   \
        for (int c_ = 0; c_ < 20; c_++) {                   \
            float y_ = 0.f;                                 \
            _Pragma("unroll")                               \
            for (int a_ = 0; a_ < 20; a_++)                 \
                y_ += comp[a_ * 20 + c_] * x[a_];           \
            q += y_ * y_;                                   \
        }                                                   \
    } while (0)

__global__ void k_init(float* __restrict__ kl)
{
    // count = 256*20*15640 = 80,076,800 ; per-elem const = -(log1.5+0.5*log(2pi))
    kl[0] = (float)(-80076800.0 * 1.3244036413128371);
}

__global__ __launch_bounds__(256, 4) void k_main(
    const float* __restrict__ comp,
    const float* __restrict__ wb0, const float* __restrict__ wd0,
    const float* __restrict__ wb1, const float* __restrict__ wd1,
    const float* __restrict__ wb2, const float* __restrict__ wd2,
    const float* __restrict__ wb3, const float* __restrict__ wd3,
    const float* __restrict__ wb4, const float* __restrict__ wd4,
    const float* __restrict__ wb5, const float* __restrict__ wd5,
    const float* __restrict__ wb6, const float* __restrict__ wd6,
    const int* __restrict__ regions_oi,
    __hip_bfloat16* __restrict__ w2,
    float* __restrict__ s_part, float* __restrict__ kl_out)
{
    __shared__ float red[4 * 20];
    __shared__ float klp[4];

    const int tid = threadIdx.x;
    const int r = blockIdx.x >> 5;
    const int tile = blockIdx.x & 31;
    const int base = tile * TBINS;
    const int r0 = regions_oi[r];

    const float* __restrict__ p6 = wd6 + (size_t)r0 * (20 * 8000);
    const float* __restrict__ p5 = wd5 + (size_t)r0 * (20 * 4000);
    const float* __restrict__ p4 = wd4 + (size_t)r0 * (20 * 2000);
    const float* __restrict__ p3 = wd3 + (size_t)r0 * (20 * 1000);
    const float* __restrict__ p2 = wd2 + (size_t)r0 * (20 * 400);
    const float* __restrict__ p1 = wd1 + (size_t)r0 * (20 * 200);
    const float* __restrict__ p0 = wd0 + (size_t)r0 * (20 * 40);
    const float* __restrict__ b6 = wb6 + (size_t)r0 * 8000;
    const float* __restrict__ b5 = wb5 + (size_t)r0 * 4000;
    const float* __restrict__ b4 = wb4 + (size_t)r0 * 2000;
    const float* __restrict__ b3 = wb3 + (size_t)r0 * 1000;
    const float* __restrict__ b2 = wb2 + (size_t)r0 * 400;
    const float* __restrict__ b1 = wb1 + (size_t)r0 * 200;
    const float* __restrict__ b0 = wb0 + (size_t)r0 * 40;

    float q = 0.f;
    float sexp[20];
#pragma unroll
    for (int c = 0; c < 20; c++) sexp[c] = 0.f;

    // ---- phase A: w for one bin + L6 quad ----
    if (tid < TBINS) {
        const int j = base + tid;
        const int i5 = j >> 1, i4 = j >> 2, i3 = j >> 3;
        const int i2 = j / 20, i1 = j / 40, i0 = j / 200;

        float cs[20];
#pragma unroll
        for (int a = 0; a < 20; a++)
            cs[a] = p5[a * 4000 + i5] + p4[a * 2000 + i4] + p3[a * 1000 + i3]
                  + p2[a * 400 + i2] + p1[a * 200 + i1] + p0[a * 40 + i0];

        float x6[20];
#pragma unroll
        for (int a = 0; a < 20; a++) x6[a] = p6[(size_t)a * 8000 + j];

        const float bb = b6[j] + b5[i5] + b4[i4] + b3[i3] + b2[i2] + b1[i1]
                       + b0[i0];

        __hip_bfloat16* wp = w2 + (size_t)(r * 20) * 8000 + j;
#pragma unroll
        for (int c = 0; c < 20; c++) {
            float y6 = 0.f, ys = 0.f;
#pragma unroll
            for (int a = 0; a < 20; a++) {
                const float cc = comp[a * 20 + c];   // uniform -> s_load
                y6 += cc * x6[a];
                ys += cc * cs[a];
            }
            q += y6 * y6;
            const float w = bb + y6 + ys;
            wp[(size_t)c * 8000] = __float2bfloat16(w);
            // |w| small (~<4): unnormalized exp-sum safe in f32
            sexp[c] += __expf(w);
        }
    }

    // ---- phase B: L5/L4/L3 quads, per-tile exclusive columns (L1-hot) ----
    {
        const int lo4 = (base + 3) >> 2, hi4 = (base + TBINS + 3) >> 2;
        const int lo3 = (base + 7) >> 3, hi3 = (base + TBINS + 7) >> 3;
        const int n4 = hi4 - lo4, n3 = hi3 - lo3;
        const int nB = 125 + n4 + n3;
        if (tid < nB) {
            const float* P; int K, col;
            if (tid < 125)            { P = p5; K = 4000; col = (base >> 1) + tid; }
            else if (tid < 125 + n4)  { P = p4; K = 2000; col = lo4 + tid - 125; }
            else                      { P = p3; K = 1000; col = lo3 + tid - 125 - n4; }
            float x[20];
#pragma unroll
            for (int a = 0; a < 20; a++) x[a] = P[(size_t)a * K + col];
            YQUAD(x);
        }
    }

    // ---- reductions ----
#pragma unroll
    for (int c = 0; c < 20; c++) {
        float s = sexp[c];
#pragma unroll
        for (int off = 32; off > 0; off >>= 1) s += __shfl_down(s, off, 64);
        if ((tid & 63) == 0) red[(tid >> 6) * 20 + c] = s;
    }
#pragma unroll
    for (int off = 32; off > 0; off >>= 1) q += __shfl_down(q, off, 64);
    if ((tid & 63) == 0) klp[tid >> 6] = q;
    __syncthreads();
    if (tid < 20)
        s_part[(size_t)blockIdx.x * 20 + tid] =
            red[tid] + red[20 + tid] + red[40 + tid] + red[60 + tid];
    if (tid == 0)
        atomicAdd(kl_out, (klp[0] + klp[1] + klp[2] + klp[3]) * (-0.5f / 2.25f));
}

// KL quads for levels 0..2 (40+200+400 = 640 cols per region, 13 MB total)
__global__ __launch_bounds__(256, 2) void k_klc(
    const float* __restrict__ comp,
    const float* __restrict__ wd0, const float* __restrict__ wd1,
    const float* __restrict__ wd2,
    const int* __restrict__ regions_oi, float* __restrict__ kl_out)
{
    __shared__ float klp[4];
    const int tid = threadIdx.x;
    const int r0 = regions_oi[blockIdx.x];
    const float* __restrict__ p2 = wd2 + (size_t)r0 * (20 * 400);
    const float* __restrict__ p1 = wd1 + (size_t)r0 * (20 * 200);
    const float* __restrict__ p0 = wd0 + (size_t)r0 * (20 * 40);

    float q = 0.f;
#pragma unroll 1
    for (int it = 0; it < 3; it++) {
        const int u = it * 256 + tid;
        if (u >= 640) break;
        const float* P; int K, col;
        if (u < 400)      { P = p2; K = 400; col = u; }
        else if (u < 600) { P = p1; K = 200; col = u - 400; }
        else              { P = p0; K = 40;  col = u - 600; }
        float x[20];
#pragma unroll
        for (int a = 0; a < 20; a++) x[a] = P[a * K + col];
        YQUAD(x);
    }
#pragma unroll
    for (int off = 32; off > 0; off >>= 1) q += __shfl_down(q, off, 64);
    if ((tid & 63) == 0) klp[tid >> 6] = q;
    __syncthreads();
    if (tid == 0)
        atomicAdd(kl_out, (klp[0] + klp[1] + klp[2] + klp[3]) * (-0.5f / 2.25f));
}

__global__ void k_sub(const float* __restrict__ s_part, float* __restrict__ sub)
{
    const int i = blockIdx.x * 256 + threadIdx.x;
    if (i >= NROI * NC) return;
    const int r = i / 20, c = i % 20;
    float s = 0.f;
#pragma unroll 1
    for (int t = 0; t < NTILE; t++) s += s_part[(size_t)(r * NTILE + t) * 20 + c];
    sub[i] = logf(s) + 3.2188758248682006f;   // + log(25)
}

__global__ void k_gather(const int* __restrict__ lri, const int* __restrict__ lci,
                         const int* __restrict__ cli, const int* __restrict__ coords,
                         const __hip_bfloat16* __restrict__ w2,
                         const float* __restrict__ sub,
                         float* __restrict__ out)
{
    const int i = blockIdx.x * 256 + threadIdx.x;
    if (i >= NCUTS) return;
    const int r = lri[i];
    const int c = cli[lci[i]];
    int co = coords[i];
    co = co < 0 ? 0 : (co > 199999 ? 199999 : co);
    const int bin = co / 25;
    const int rc = r * 20 + c;
    out[i] = __bfloat162float(w2[(size_t)rc * 8000 + bin]) - sub[rc];
}

extern "C" void kernel_launch(void* const* d_in, const int* in_sizes, int n_in,
                              void* d_out, int out_size, void* d_ws, size_t ws_size,
                              hipStream_t stream)
{
    const float* comp = (const float*)d_in[0];
    const float* wb[7];
    const float* wd[7];
    if (in_sizes[2] == 400000) {
        for (int l = 0; l < 7; l++) { wb[l] = (const float*)d_in[1 + 2 * l]; wd[l] = (const float*)d_in[2 + 2 * l]; }
    } else {
        for (int l = 0; l < 7; l++) { wb[l] = (const float*)d_in[1 + l]; wd[l] = (const float*)d_in[8 + l]; }
    }
    const int* regions_oi = (const int*)d_in[15];
    const int* lri   = (const int*)d_in[16];
    const int* lci   = (const int*)d_in[17];
    const int* cli   = (const int*)d_in[18];
    const int* coords= (const int*)d_in[19];
    float* out = (float*)d_out;

    __hip_bfloat16* w2 = (__hip_bfloat16*)d_ws;                     // 81.92 MB
    float* s_part = (float*)(w2 + (size_t)NROI * NC * NFINAL);      // 8192*20 f32
    float* sub    = s_part + (size_t)NROI * NTILE * 20;             // 5120 f32
    const size_t need = (size_t)NROI * NC * NFINAL * 2
                      + ((size_t)NROI * NTILE * 20 + NROI * NC) * sizeof(float);
    if (ws_size < need) return;

    k_init<<<1, 1, 0, stream>>>(out + NCUTS);
    k_main<<<NROI * NTILE, 256, 0, stream>>>(comp,
        wb[0], wd[0], wb[1], wd[1], wb[2], wd[2], wb[3], wd[3],
        wb[4], wd[4], wb[5], wd[5], wb[6], wd[6],
        regions_oi, w2, s_part, out + NCUTS);
    k_klc<<<NROI, 256, 0, stream>>>(comp, wd[0], wd[1], wd[2],
        regions_oi, out + NCUTS);
    k_sub<<<(NROI * NC + 255) / 256, 256, 0, stream>>>(s_part, sub);
    k_gather<<<(NCUTS + 255) / 256, 256, 0, stream>>>(lri, lci, cli, coords,
        w2, sub, out);
}

// Round 7
// 255.662 us; speedup vs baseline: 2.5839x; 2.5839x over previous
//
#include <hip/hip_runtime.h>
#include <hip/hip_bf16.h>
#include <math.h>

// SharedLora on MI355X — round 7.
// r2 structure (LDS-staged level-sum U) + c-blocking (thread = 5 clusters x
// 4 bins per U read: LDS amplification 20x -> 4x) + fused KL quads:
//   P0: stage U[20][400] = sum of 7 delta levels, bias[400] = sum of 7 biases
//   PA: wave w = clusters 5w..5w+4; thread handles float4 of bins:
//       acc[5] = bias + sum_a comp[a][c]*U[a][j4]; bf16 store; sexp[5] regs
//   PQ: KL quads for L6/L5/L4/L3 via triangular doubled-Gram (230 FMA/col),
//       re-reading L2-hot columns. L0-2 in k_klc. No separate KL pass.

#define NROI 256
#define NC 20
#define NFINAL 8000
#define NCUTS 500000
#define TBINS 400
#define NTILE 20           // 8000 / TBINS
#define UPAD 404

__global__ void k_init(const float* __restrict__ comp,
                       float* __restrict__ g2, float* __restrict__ kl)
{
    const int tid = threadIdx.x;
    if (tid == 0) kl[0] = (float)(-80076800.0 * 1.3244036413128371);
    for (int i = tid; i < 400; i += 256) {
        const int a = i / 20, b = i % 20;
        float s = 0.f;
#pragma unroll
        for (int c = 0; c < 20; c++) s += comp[a * 20 + c] * comp[b * 20 + c];
        // upper-triangular, off-diagonal doubled: q = sum_a x_a * sum_{b>=a} G2 x_b
        g2[i] = (b < a) ? 0.f : (b == a ? s : 2.f * s);
    }
}

__global__ __launch_bounds__(256, 2) void k_main(
    const float* __restrict__ comp, const float* __restrict__ g2,
    const float* __restrict__ wb0, const float* __restrict__ wd0,
    const float* __restrict__ wb1, const float* __restrict__ wd1,
    const float* __restrict__ wb2, const float* __restrict__ wd2,
    const float* __restrict__ wb3, const float* __restrict__ wd3,
    const float* __restrict__ wb4, const float* __restrict__ wd4,
    const float* __restrict__ wb5, const float* __restrict__ wd5,
    const float* __restrict__ wb6, const float* __restrict__ wd6,
    const int* __restrict__ regions_oi,
    __hip_bfloat16* __restrict__ w2,
    float* __restrict__ s_part, float* __restrict__ kl_out)
{
    __shared__ float U_sh[20 * UPAD];   // 32,320 B
    __shared__ float bias_sh[TBINS];    // 1,600 B
    __shared__ float klp[4];

    const int tid = threadIdx.x;
    const int r = blockIdx.x / NTILE;
    const int tile = blockIdx.x - r * NTILE;
    const int base = tile * TBINS;
    const int r0 = regions_oi[r];

    const float* __restrict__ p6 = wd6 + (size_t)r0 * (20 * 8000);
    const float* __restrict__ p5 = wd5 + (size_t)r0 * (20 * 4000);
    const float* __restrict__ p4 = wd4 + (size_t)r0 * (20 * 2000);
    const float* __restrict__ p3 = wd3 + (size_t)r0 * (20 * 1000);
    const float* __restrict__ p2 = wd2 + (size_t)r0 * (20 * 400);
    const float* __restrict__ p1 = wd1 + (size_t)r0 * (20 * 200);
    const float* __restrict__ p0 = wd0 + (size_t)r0 * (20 * 40);
    const float* __restrict__ b6 = wb6 + (size_t)r0 * 8000;
    const float* __restrict__ b5 = wb5 + (size_t)r0 * 4000;
    const float* __restrict__ b4 = wb4 + (size_t)r0 * 2000;
    const float* __restrict__ b3 = wb3 + (size_t)r0 * 1000;
    const float* __restrict__ b2 = wb2 + (size_t)r0 * 400;
    const float* __restrict__ b1 = wb1 + (size_t)r0 * 200;
    const float* __restrict__ b0 = wb0 + (size_t)r0 * 40;

    // ---- P0: stage U (2000 float4 units) + bias (100 units) ----
#pragma unroll 1
    for (int it = 0; it < 8; it++) {
        const int u = it * 256 + tid;
        if (u >= 2000) break;
        const int a = u / 100, jq = u - a * 100;
        const float4 v6 = *(const float4*)(p6 + (size_t)a * 8000 + base + 4 * jq);
        const float2 v5 = *(const float2*)(p5 + a * 4000 + (base >> 1) + 2 * jq);
        const float sc = p4[a * 2000 + (base >> 2) + jq]
                       + p3[a * 1000 + 50 * tile + (jq >> 1)]
                       + p2[a * 400 + 20 * tile + jq / 5]
                       + p1[a * 200 + 10 * tile + jq / 10]
                       + p0[a * 40 + 2 * tile + jq / 50];
        const float c01 = v5.x + sc, c23 = v5.y + sc;
        float4 uu;
        uu.x = v6.x + c01; uu.y = v6.y + c01;
        uu.z = v6.z + c23; uu.w = v6.w + c23;
        *(float4*)(&U_sh[a * UPAD + 4 * jq]) = uu;
    }
    if (tid < 100) {
        const int jq = tid;
        const float4 v6 = *(const float4*)(b6 + base + 4 * jq);
        const float2 v5 = *(const float2*)(b5 + (base >> 1) + 2 * jq);
        const float sc = b4[(base >> 2) + jq] + b3[50 * tile + (jq >> 1)]
                       + b2[20 * tile + jq / 5] + b1[10 * tile + jq / 10]
                       + b0[2 * tile + jq / 50];
        const float c01 = v5.x + sc, c23 = v5.y + sc;
        float4 uu;
        uu.x = v6.x + c01; uu.y = v6.y + c01;
        uu.z = v6.z + c23; uu.w = v6.w + c23;
        *(float4*)(&bias_sh[4 * jq]) = uu;
    }
    __syncthreads();

    // ---- PA: wave w = clusters [5w, 5w+5); lane covers j4 = lane, lane+64 ----
    const int wv = tid >> 6, lane = tid & 63;
    const int c0 = wv * 5;
    float sexp[5];
#pragma unroll
    for (int k = 0; k < 5; k++) sexp[k] = 0.f;

#pragma unroll 1
    for (int it = 0; it < 2; it++) {
        const int jq = it * 64 + lane;
        if (jq >= 100) break;
        const float4 bi = *(const float4*)(&bias_sh[4 * jq]);
        float4 a0 = bi, a1 = bi, a2 = bi, a3 = bi, a4 = bi;
#pragma unroll
        for (int a = 0; a < 20; a++) {
            const float4 u = *(const float4*)(&U_sh[a * UPAD + 4 * jq]);
            const float f0 = comp[a * 20 + c0 + 0];   // uniform -> s_load
            const float f1 = comp[a * 20 + c0 + 1];
            const float f2 = comp[a * 20 + c0 + 2];
            const float f3 = comp[a * 20 + c0 + 3];
            const float f4 = comp[a * 20 + c0 + 4];
            a0.x += f0 * u.x; a0.y += f0 * u.y; a0.z += f0 * u.z; a0.w += f0 * u.w;
            a1.x += f1 * u.x; a1.y += f1 * u.y; a1.z += f1 * u.z; a1.w += f1 * u.w;
            a2.x += f2 * u.x; a2.y += f2 * u.y; a2.z += f2 * u.z; a2.w += f2 * u.w;
            a3.x += f3 * u.x; a3.y += f3 * u.y; a3.z += f3 * u.z; a3.w += f3 * u.w;
            a4.x += f4 * u.x; a4.y += f4 * u.y; a4.z += f4 * u.z; a4.w += f4 * u.w;
        }
        float4 accs[5] = {a0, a1, a2, a3, a4};
#pragma unroll
        for (int k = 0; k < 5; k++) {
            const float4 acc = accs[k];
            union { __hip_bfloat162 h2[2]; uint2 u2; } pk;
            pk.h2[0] = __float22bfloat162_rn(make_float2(acc.x, acc.y));
            pk.h2[1] = __float22bfloat162_rn(make_float2(acc.z, acc.w));
            *(uint2*)(w2 + (size_t)(r * 20 + c0 + k) * 8000 + base + 4 * jq) = pk.u2;
            // |w| small (~<4): unnormalized exp-sum safe in f32
            sexp[k] += __expf(acc.x) + __expf(acc.y) + __expf(acc.z) + __expf(acc.w);
        }
    }
    // wave-reduce sexp and write s_part (wave-exclusive clusters)
#pragma unroll
    for (int k = 0; k < 5; k++) {
        float s = sexp[k];
#pragma unroll
        for (int off = 32; off > 0; off >>= 1) s += __shfl_down(s, off, 64);
        if (lane == 0) s_part[(size_t)blockIdx.x * 20 + c0 + k] = s;
    }

    // ---- PQ: KL quads for L6/L5/L4/L3 columns of this tile (L2-hot) ----
    float q = 0.f;
#pragma unroll 1
    for (int it = 0; it < 3; it++) {
        const int u = it * 256 + tid;
        if (u >= 750) break;
        const float* P; int K, col;
        if (u < 400)      { P = p6; K = 8000; col = base + u; }
        else if (u < 600) { P = p5; K = 4000; col = (base >> 1) + u - 400; }
        else if (u < 700) { P = p4; K = 2000; col = (base >> 2) + u - 600; }
        else              { P = p3; K = 1000; col = 50 * tile + u - 700; }
        float x[20];
#pragma unroll
        for (int a = 0; a < 20; a++) x[a] = P[(size_t)a * K + col];
#pragma unroll
        for (int a = 0; a < 20; a++) {
            float t = g2[a * 20 + a] * x[a];
#pragma unroll
            for (int b = a + 1; b < 20; b++) t += g2[a * 20 + b] * x[b];
            q += x[a] * t;
        }
    }
#pragma unroll
    for (int off = 32; off > 0; off >>= 1) q += __shfl_down(q, off, 64);
    if (lane == 0) klp[wv] = q;
    __syncthreads();
    if (tid == 0)
        atomicAdd(kl_out, (klp[0] + klp[1] + klp[2] + klp[3]) * (-0.5f / 2.25f));
}

// KL quads for levels 0..2 (40+200+400 = 640 cols per region)
__global__ __launch_bounds__(256, 2) void k_klc(
    const float* __restrict__ g2,
    const float* __restrict__ wd0, const float* __restrict__ wd1,
    const float* __restrict__ wd2,
    const int* __restrict__ regions_oi, float* __restrict__ kl_out)
{
    __shared__ float klp[4];
    const int tid = threadIdx.x;
    const int r0 = regions_oi[blockIdx.x];
    const float* __restrict__ p2 = wd2 + (size_t)r0 * (20 * 400);
    const float* __restrict__ p1 = wd1 + (size_t)r0 * (20 * 200);
    const float* __restrict__ p0 = wd0 + (size_t)r0 * (20 * 40);

    float q = 0.f;
#pragma unroll 1
    for (int it = 0; it < 3; it++) {
        const int u = it * 256 + tid;
        if (u >= 640) break;
        const float* P; int K, col;
        if (u < 400)      { P = p2; K = 400; col = u; }
        else if (u < 600) { P = p1; K = 200; col = u - 400; }
        else              { P = p0; K = 40;  col = u - 600; }
        float x[20];
#pragma unroll
        for (int a = 0; a < 20; a++) x[a] = P[a * K + col];
#pragma unroll
        for (int a = 0; a < 20; a++) {
            float t = g2[a * 20 + a] * x[a];
#pragma unroll
            for (int b = a + 1; b < 20; b++) t += g2[a * 20 + b] * x[b];
            q += x[a] * t;
        }
    }
#pragma unroll
    for (int off = 32; off > 0; off >>= 1) q += __shfl_down(q, off, 64);
    if ((tid & 63) == 0) klp[tid >> 6] = q;
    __syncthreads();
    if (tid == 0)
        atomicAdd(kl_out, (klp[0] + klp[1] + klp[2] + klp[3]) * (-0.5f / 2.25f));
}

__global__ void k_sub(const float* __restrict__ s_part, float* __restrict__ sub)
{
    const int i = blockIdx.x * 256 + threadIdx.x;
    if (i >= NROI * NC) return;
    const int r = i / 20, c = i % 20;
    float s = 0.f;
#pragma unroll 1
    for (int t = 0; t < NTILE; t++) s += s_part[(size_t)(r * NTILE + t) * 20 + c];
    sub[i] = logf(s) + 3.2188758248682006f;   // + log(25)
}

__global__ void k_gather(const int* __restrict__ lri, const int* __restrict__ lci,
                         const int* __restrict__ cli, const int* __restrict__ coords,
                         const __hip_bfloat16* __restrict__ w2,
                         const float* __restrict__ sub,
                         float* __restrict__ out)
{
    const int i = blockIdx.x * 256 + threadIdx.x;
    if (i >= NCUTS) return;
    const int r = lri[i];
    const int c = cli[lci[i]];
    int co = coords[i];
    co = co < 0 ? 0 : (co > 199999 ? 199999 : co);
    const int bin = co / 25;
    const int rc = r * 20 + c;
    out[i] = __bfloat162float(w2[(size_t)rc * 8000 + bin]) - sub[rc];
}

extern "C" void kernel_launch(void* const* d_in, const int* in_sizes, int n_in,
                              void* d_out, int out_size, void* d_ws, size_t ws_size,
                              hipStream_t stream)
{
    const float* comp = (const float*)d_in[0];
    const float* wb[7];
    const float* wd[7];
    if (in_sizes[2] == 400000) {
        for (int l = 0; l < 7; l++) { wb[l] = (const float*)d_in[1 + 2 * l]; wd[l] = (const float*)d_in[2 + 2 * l]; }
    } else {
        for (int l = 0; l < 7; l++) { wb[l] = (const float*)d_in[1 + l]; wd[l] = (const float*)d_in[8 + l]; }
    }
    const int* regions_oi = (const int*)d_in[15];
    const int* lri   = (const int*)d_in[16];
    const int* lci   = (const int*)d_in[17];
    const int* cli   = (const int*)d_in[18];
    const int* coords= (const int*)d_in[19];
    float* out = (float*)d_out;

    __hip_bfloat16* w2 = (__hip_bfloat16*)d_ws;                     // 81.92 MB
    float* s_part = (float*)(w2 + (size_t)NROI * NC * NFINAL);      // 5120*20 f32
    float* sub    = s_part + (size_t)NROI * NTILE * 20;             // 5120 f32
    float* g2buf  = sub + NROI * NC;                                // 400 f32
    const size_t need = (size_t)NROI * NC * NFINAL * 2
                      + ((size_t)NROI * NTILE * 20 + NROI * NC + 400) * sizeof(float);
    if (ws_size < need) return;

    k_init<<<1, 256, 0, stream>>>(comp, g2buf, out + NCUTS);
    k_main<<<NROI * NTILE, 256, 0, stream>>>(comp, g2buf,
        wb[0], wd[0], wb[1], wd[1], wb[2], wd[2], wb[3], wd[3],
        wb[4], wd[4], wb[5], wd[5], wb[6], wd[6],
        regions_oi, w2, s_part, out + NCUTS);
    k_klc<<<NROI, 256, 0, stream>>>(g2buf, wd[0], wd[1], wd[2],
        regions_oi, out + NCUTS);
    k_sub<<<(NROI * NC + 255) / 256, 256, 0, stream>>>(s_part, sub);
    k_gather<<<(NCUTS + 255) / 256, 256, 0, stream>>>(lri, lci, cli, coords,
        w2, sub, out);
}